// Round 8
// baseline (262.223 us; speedup 1.0000x reference)
//
#include <hip/hip_runtime.h>
#include <stdint.h>

#define TPB 256
#define SPAN 256        // nodes per dest bucket (bucket = col>>8)
#define LSH 8           // log2(SPAN)
#define PART_B 128      // partition blocks (fewer blocks -> longer runs)
#define PART_T 1024     // threads in hist/partition/sort kernels
#define SCAN_T 1024
#define SCAN_B 4096     // elements per scan block (1024 thr x 4)

// ---------------------------------------------------------------------------
// GCN 3-layer forward on MI355X.
// R8: R7 pipeline, partition geometry fix. R7's p_part had 5.5x write amp
// (98us): SPAN=128/PART_B=256 -> 128B runs per (bucket,block), every cache
// line co-written by 2 blocks (cross-XCD partial-line evictions). Now
// SPAN=256/PART_B=128 -> 512B runs, ~4x fewer shared-line boundaries.
// Pipeline: p_hist | scan (in place) | p_part (bucket-grouped bpack,
// (row<<8)|ldest) | p_sort (per-bucket LDS counting sort -> csr_row,
// window-local writes; emits indptr+dinv) | xw1d | 3x CSR gather w/ fused
// node transforms. agg[c] = dinv[c]*(sum_in dxw[r] + dxw[c]).
// WS ~56.3MB (<= 57.6MB proven in R4). R3 atomic-push fallback kept.
// ---------------------------------------------------------------------------

// ---------------- bucket partition ----------------

// Per-block bucket histogram: H[b][blk] = #edges of block blk with dest bucket b.
__global__ __launch_bounds__(PART_T) void p_hist(
    const int* __restrict__ col, uint32_t* __restrict__ H,
    int NB, int E, int PBE) {
    __shared__ uint32_t cnt[1024];
    for (int i = threadIdx.x; i < NB; i += PART_T) cnt[i] = 0u;
    __syncthreads();
    int blk = blockIdx.x;
    int s = blk * PBE, e = min(E, s + PBE);
    for (int i = s + threadIdx.x; i < e; i += PART_T)
        atomicAdd(&cnt[col[i] >> LSH], 1u);
    __syncthreads();
    for (int i = threadIdx.x; i < NB; i += PART_T)
        H[(size_t)i * PART_B + blk] = cnt[i];
}

// Scan phase 1 (in-place safe: reads then writes same indices).
__global__ __launch_bounds__(SCAN_T) void k_scan1(
    const unsigned int* __restrict__ in, unsigned int* __restrict__ partial,
    unsigned int* __restrict__ bsum, int M) {
    __shared__ unsigned int sm[SCAN_T];
    int tid  = threadIdx.x;
    int base = blockIdx.x * SCAN_B + tid * 4;
    unsigned int v0 = (base + 0 < M) ? in[base + 0] : 0u;
    unsigned int v1 = (base + 1 < M) ? in[base + 1] : 0u;
    unsigned int v2 = (base + 2 < M) ? in[base + 2] : 0u;
    unsigned int v3 = (base + 3 < M) ? in[base + 3] : 0u;
    unsigned int s = v0 + v1 + v2 + v3;
    sm[tid] = s;
    __syncthreads();
    for (int off = 1; off < SCAN_T; off <<= 1) {
        unsigned int t = (tid >= off) ? sm[tid - off] : 0u;
        __syncthreads();
        sm[tid] += t;
        __syncthreads();
    }
    unsigned int excl = sm[tid] - s;
    if (base + 0 < M) partial[base + 0] = excl;
    if (base + 1 < M) partial[base + 1] = excl + v0;
    if (base + 2 < M) partial[base + 2] = excl + v0 + v1;
    if (base + 3 < M) partial[base + 3] = excl + v0 + v1 + v2;
    if (tid == SCAN_T - 1) bsum[blockIdx.x] = sm[SCAN_T - 1];
}

__global__ void k_scan2(unsigned int* __restrict__ bsum, int nb) {
    if (threadIdx.x == 0 && blockIdx.x == 0) {
        unsigned int run = 0;
        for (int i = 0; i < nb; ++i) {
            unsigned int t = bsum[i];
            bsum[i] = run;
            run += t;
        }
    }
}

// Scan phase 3 (in-place safe: outp may alias partial).
__global__ __launch_bounds__(TPB) void k_scan3(
    const unsigned int* __restrict__ partial, const unsigned int* __restrict__ bsum,
    unsigned int* __restrict__ outp, int M, int E) {
    int i = blockIdx.x * TPB + threadIdx.x;
    if (i < M) outp[i] = partial[i] + bsum[i / SCAN_B];
    if (i == 0) outp[M] = (unsigned int)E;
}

// Partition: write bpack[slot] = (row<<8)|ldest, bucket-grouped.
__global__ __launch_bounds__(PART_T) void p_part(
    const int* __restrict__ row, const int* __restrict__ col,
    const uint32_t* __restrict__ O, uint32_t* __restrict__ bpack,
    int NB, int E, int PBE) {
    __shared__ uint32_t cur[1024];
    int blk = blockIdx.x;
    for (int i = threadIdx.x; i < NB; i += PART_T)
        cur[i] = O[(size_t)i * PART_B + blk];
    __syncthreads();
    int s = blk * PBE, e = min(E, s + PBE);
    for (int i = s + threadIdx.x; i < e; i += PART_T) {
        int c = col[i];
        uint32_t slot = atomicAdd(&cur[c >> LSH], 1u);
        bpack[slot] = ((uint32_t)row[i] << LSH) | (uint32_t)(c & (SPAN - 1));
    }
}

// Per-bucket counting sort: bpack slice -> node-sorted csr_row (same window),
// emitting indptr + dinv from the local histogram. Writes stay in the
// bucket's window -> no write amplification.
__global__ __launch_bounds__(PART_T) void p_sort(
    const uint32_t* __restrict__ bpack, const uint32_t* __restrict__ O,
    int* __restrict__ csr_row, unsigned int* __restrict__ indptr,
    float* __restrict__ dinv, int NB, int N, int E) {
    __shared__ uint32_t hist[SPAN];
    __shared__ uint32_t cur[SPAN];
    int b = blockIdx.x;
    int t = threadIdx.x;
    if (t < SPAN) hist[t] = 0u;
    __syncthreads();
    uint32_t s = O[(size_t)b * PART_B];
    uint32_t e = (b + 1 < NB) ? O[(size_t)(b + 1) * PART_B] : (uint32_t)E;
    for (uint32_t i = s + t; i < e; i += PART_T)
        atomicAdd(&hist[bpack[i] & (SPAN - 1)], 1u);
    __syncthreads();
    if (t < SPAN) cur[t] = hist[t];
    __syncthreads();
    for (int off = 1; off < SPAN; off <<= 1) {  // Hillis-Steele inclusive scan
        uint32_t v = (t < SPAN && t >= off) ? cur[t - off] : 0u;
        __syncthreads();
        if (t < SPAN) cur[t] += v;
        __syncthreads();
    }
    if (t < SPAN) {
        uint32_t excl = cur[t] - hist[t];
        int n = b * SPAN + t;
        if (n < N) {
            indptr[n] = s + excl;
            dinv[n]   = rsqrtf((float)(hist[t] + 1u));  // +1 = self loop
            if (n == N - 1) indptr[N] = (unsigned int)E;
        }
        cur[t] = s + excl;  // global cursor for this node
    }
    __syncthreads();
    for (uint32_t i = s + t; i < e; i += PART_T) {
        uint32_t v = bpack[i];
        uint32_t slot = atomicAdd(&cur[v & (SPAN - 1)], 1u);
        csr_row[slot] = (int)(v >> LSH);
    }
}

// ---------------- node / gather kernels (main path) ----------------

// dxw1 = dinv * (x @ W1), wave per node.
__global__ __launch_bounds__(TPB) void k_xw1d(
    const float* __restrict__ x, const float* __restrict__ W1,
    const float* __restrict__ dinv, float* __restrict__ dxw1, int N) {
    __shared__ float sW[512];  // 128 x 4
    for (int t = threadIdx.x; t < 512; t += TPB) sW[t] = W1[t];
    __syncthreads();
    int gid  = blockIdx.x * TPB + threadIdx.x;
    int node = gid >> 6;
    int lane = threadIdx.x & 63;
    if (node >= N) return;
    float2 v = *(const float2*)(x + (size_t)node * 128 + 2 * lane);
    const float* w0 = &sW[(2 * lane) * 4];
    const float* w1 = &sW[(2 * lane + 1) * 4];
    float a[4];
#pragma unroll
    for (int j = 0; j < 4; ++j) a[j] = v.x * w0[j] + v.y * w1[j];
#pragma unroll
    for (int off = 32; off > 0; off >>= 1) {
#pragma unroll
        for (int j = 0; j < 4; ++j) a[j] += __shfl_down(a[j], off);
    }
    if (lane == 0) {
        float d = dinv[node];
        *(float4*)(dxw1 + (size_t)node * 4) =
            make_float4(d * a[0], d * a[1], d * a[2], d * a[3]);
    }
}

// Gather layer (4-wide in / 4-wide out): 16 threads/node.
__global__ __launch_bounds__(TPB) void k_gather44(
    const unsigned int* __restrict__ indptr, const int* __restrict__ csr_row,
    const float* __restrict__ dinv, const float* __restrict__ dxw_in,
    const float* __restrict__ b, const float* __restrict__ W,
    float* __restrict__ dxw_out, int N) {
    int gid  = blockIdx.x * TPB + threadIdx.x;
    int node = gid >> 4;
    int sub  = gid & 15;
    if (node >= N) return;
    int e0 = (int)indptr[node], e1 = (int)indptr[node + 1];
    float4 acc = make_float4(0.f, 0.f, 0.f, 0.f);
    for (int j = e0 + sub; j < e1; j += 16) {
        int r = csr_row[j];
        float4 m = *(const float4*)(dxw_in + (size_t)r * 4);
        acc.x += m.x; acc.y += m.y; acc.z += m.z; acc.w += m.w;
    }
#pragma unroll
    for (int off = 1; off < 16; off <<= 1) {
        acc.x += __shfl_xor(acc.x, off);
        acc.y += __shfl_xor(acc.y, off);
        acc.z += __shfl_xor(acc.z, off);
        acc.w += __shfl_xor(acc.w, off);
    }
    if (sub == 0) {
        float d = dinv[node];
        float4 sv = *(const float4*)(dxw_in + (size_t)node * 4);
        float h0 = fmaxf(d * (acc.x + sv.x) + b[0], 0.f);
        float h1 = fmaxf(d * (acc.y + sv.y) + b[1], 0.f);
        float h2 = fmaxf(d * (acc.z + sv.z) + b[2], 0.f);
        float h3 = fmaxf(d * (acc.w + sv.w) + b[3], 0.f);
        float o[4];
#pragma unroll
        for (int j = 0; j < 4; ++j)
            o[j] = h0 * W[0 * 4 + j] + h1 * W[1 * 4 + j] +
                   h2 * W[2 * 4 + j] + h3 * W[3 * 4 + j];
        *(float4*)(dxw_out + (size_t)node * 4) =
            make_float4(d * o[0], d * o[1], d * o[2], d * o[3]);
    }
}

// Gather layer (4-wide in / 2-wide out): 16 threads/node.
__global__ __launch_bounds__(TPB) void k_gather42(
    const unsigned int* __restrict__ indptr, const int* __restrict__ csr_row,
    const float* __restrict__ dinv, const float* __restrict__ dxw_in,
    const float* __restrict__ b, const float* __restrict__ W,
    float* __restrict__ dxw_out, int N) {
    int gid  = blockIdx.x * TPB + threadIdx.x;
    int node = gid >> 4;
    int sub  = gid & 15;
    if (node >= N) return;
    int e0 = (int)indptr[node], e1 = (int)indptr[node + 1];
    float4 acc = make_float4(0.f, 0.f, 0.f, 0.f);
    for (int j = e0 + sub; j < e1; j += 16) {
        int r = csr_row[j];
        float4 m = *(const float4*)(dxw_in + (size_t)r * 4);
        acc.x += m.x; acc.y += m.y; acc.z += m.z; acc.w += m.w;
    }
#pragma unroll
    for (int off = 1; off < 16; off <<= 1) {
        acc.x += __shfl_xor(acc.x, off);
        acc.y += __shfl_xor(acc.y, off);
        acc.z += __shfl_xor(acc.z, off);
        acc.w += __shfl_xor(acc.w, off);
    }
    if (sub == 0) {
        float d = dinv[node];
        float4 sv = *(const float4*)(dxw_in + (size_t)node * 4);
        float h0 = fmaxf(d * (acc.x + sv.x) + b[0], 0.f);
        float h1 = fmaxf(d * (acc.y + sv.y) + b[1], 0.f);
        float h2 = fmaxf(d * (acc.z + sv.z) + b[2], 0.f);
        float h3 = fmaxf(d * (acc.w + sv.w) + b[3], 0.f);
        float o0 = h0 * W[0] + h1 * W[2] + h2 * W[4] + h3 * W[6];
        float o1 = h0 * W[1] + h1 * W[3] + h2 * W[5] + h3 * W[7];
        *(float2*)(dxw_out + (size_t)node * 2) = make_float2(d * o0, d * o1);
    }
}

// Final gather (2-wide): 16 threads/node; writes both outputs.
__global__ __launch_bounds__(TPB) void k_gather2out(
    const unsigned int* __restrict__ indptr, const int* __restrict__ csr_row,
    const float* __restrict__ dinv, const float* __restrict__ dxw3,
    const float* __restrict__ b3, const float* __restrict__ Wc,
    const float* __restrict__ bc,
    float* __restrict__ out, float* __restrict__ y3out, int N) {
    int gid  = blockIdx.x * TPB + threadIdx.x;
    int node = gid >> 4;
    int sub  = gid & 15;
    if (node >= N) return;
    int e0 = (int)indptr[node], e1 = (int)indptr[node + 1];
    float ax = 0.f, ay = 0.f;
    for (int j = e0 + sub; j < e1; j += 16) {
        int r = csr_row[j];
        float2 m = *(const float2*)(dxw3 + (size_t)r * 2);
        ax += m.x; ay += m.y;
    }
#pragma unroll
    for (int off = 1; off < 16; off <<= 1) {
        ax += __shfl_xor(ax, off);
        ay += __shfl_xor(ay, off);
    }
    if (sub == 0) {
        float d = dinv[node];
        float2 sv = *(const float2*)(dxw3 + (size_t)node * 2);
        float y0 = fmaxf(d * (ax + sv.x) + b3[0], 0.f);
        float y1 = fmaxf(d * (ay + sv.y) + b3[1], 0.f);
        float o[4];
#pragma unroll
        for (int j = 0; j < 4; ++j)
            o[j] = y0 * Wc[0 * 4 + j] + y1 * Wc[1 * 4 + j] + bc[j];
        *(float4*)(out + (size_t)node * 4) = make_float4(o[0], o[1], o[2], o[3]);
        *(float2*)(y3out + (size_t)node * 2) = make_float2(y0, y1);
    }
}

// ---------------- R3 fallback kernels (atomic push path) ----------------

__global__ __launch_bounds__(TPB) void k_zero_deg(unsigned int* __restrict__ deg, int N) {
    int i = blockIdx.x * TPB + threadIdx.x;
    if (i < N) deg[i] = 0u;
}

__global__ __launch_bounds__(TPB) void k_deg(
    const int* __restrict__ col, unsigned int* __restrict__ deg, int E) {
    int e = blockIdx.x * TPB + threadIdx.x;
    if (e >= E) return;
    atomicAdd(&deg[col[e]], 1u);
}

__global__ __launch_bounds__(TPB) void k_dinv(const unsigned int* __restrict__ deg,
                                              float* __restrict__ dinv, int N) {
    int i = blockIdx.x * TPB + threadIdx.x;
    if (i < N) dinv[i] = rsqrtf((float)(deg[i] + 1u));
}

__global__ __launch_bounds__(TPB) void k_xw1(
    const float* __restrict__ x, const float* __restrict__ W1,
    const float* __restrict__ dinv,
    float* __restrict__ xw, float* __restrict__ agg, int N) {
    __shared__ float sW[512];
    for (int t = threadIdx.x; t < 512; t += TPB) sW[t] = W1[t];
    __syncthreads();
    int gid  = blockIdx.x * TPB + threadIdx.x;
    int node = gid >> 6;
    int lane = threadIdx.x & 63;
    if (node >= N) return;
    float2 v = *(const float2*)(x + (size_t)node * 128 + 2 * lane);
    const float* w0 = &sW[(2 * lane) * 4];
    const float* w1 = &sW[(2 * lane + 1) * 4];
    float a[4];
#pragma unroll
    for (int j = 0; j < 4; ++j) a[j] = v.x * w0[j] + v.y * w1[j];
#pragma unroll
    for (int off = 32; off > 0; off >>= 1) {
#pragma unroll
        for (int j = 0; j < 4; ++j) a[j] += __shfl_down(a[j], off);
    }
    if (lane == 0) {
        float d  = dinv[node];
        float d2 = d * d;
        *(float4*)(xw  + (size_t)node * 4) = make_float4(a[0], a[1], a[2], a[3]);
        *(float4*)(agg + (size_t)node * 4) =
            make_float4(d2 * a[0], d2 * a[1], d2 * a[2], d2 * a[3]);
    }
}

__global__ __launch_bounds__(TPB) void k_prop4(
    const int* __restrict__ row, const int* __restrict__ col,
    const float* __restrict__ dinv,
    const float* __restrict__ xw, float* __restrict__ agg, int E) {
    int e = blockIdx.x * TPB + threadIdx.x;
    if (e >= E) return;
    int r = row[e];
    int c = col[e];
    float nv = dinv[r] * dinv[c];
    float4 m = *(const float4*)(xw + (size_t)r * 4);
    float* a = agg + (size_t)c * 4;
    atomicAdd(a + 0, nv * m.x);
    atomicAdd(a + 1, nv * m.y);
    atomicAdd(a + 2, nv * m.z);
    atomicAdd(a + 3, nv * m.w);
}

__global__ __launch_bounds__(TPB) void k_prop2(
    const int* __restrict__ row, const int* __restrict__ col,
    const float* __restrict__ dinv,
    const float* __restrict__ xw2, float* __restrict__ agg2, int E) {
    int e = blockIdx.x * TPB + threadIdx.x;
    if (e >= E) return;
    int r = row[e];
    int c = col[e];
    float nv = dinv[r] * dinv[c];
    float2 m = *(const float2*)(xw2 + (size_t)r * 2);
    float* a = agg2 + (size_t)c * 2;
    atomicAdd(a + 0, nv * m.x);
    atomicAdd(a + 1, nv * m.y);
}

__global__ __launch_bounds__(TPB) void k_node2(
    const float* __restrict__ b1, const float* __restrict__ W2,
    const float* __restrict__ dinv,
    float* __restrict__ xw, float* __restrict__ agg, int N) {
    int i = blockIdx.x * TPB + threadIdx.x;
    if (i >= N) return;
    float4 av = *(const float4*)(agg + (size_t)i * 4);
    float h0 = fmaxf(av.x + b1[0], 0.f);
    float h1 = fmaxf(av.y + b1[1], 0.f);
    float h2 = fmaxf(av.z + b1[2], 0.f);
    float h3 = fmaxf(av.w + b1[3], 0.f);
    float o[4];
#pragma unroll
    for (int j = 0; j < 4; ++j)
        o[j] = h0 * W2[0 * 4 + j] + h1 * W2[1 * 4 + j] +
               h2 * W2[2 * 4 + j] + h3 * W2[3 * 4 + j];
    float d  = dinv[i];
    float d2 = d * d;
    *(float4*)(xw  + (size_t)i * 4) = make_float4(o[0], o[1], o[2], o[3]);
    *(float4*)(agg + (size_t)i * 4) = make_float4(d2 * o[0], d2 * o[1], d2 * o[2], d2 * o[3]);
}

__global__ __launch_bounds__(TPB) void k_node3(
    const float* __restrict__ b2, const float* __restrict__ W3,
    const float* __restrict__ dinv,
    const float* __restrict__ agg,
    float* __restrict__ xw3, float* __restrict__ agg3, int N) {
    int i = blockIdx.x * TPB + threadIdx.x;
    if (i >= N) return;
    float4 av = *(const float4*)(agg + (size_t)i * 4);
    float h0 = fmaxf(av.x + b2[0], 0.f);
    float h1 = fmaxf(av.y + b2[1], 0.f);
    float h2 = fmaxf(av.z + b2[2], 0.f);
    float h3 = fmaxf(av.w + b2[3], 0.f);
    float o0 = h0 * W3[0] + h1 * W3[2] + h2 * W3[4] + h3 * W3[6];
    float o1 = h0 * W3[1] + h1 * W3[3] + h2 * W3[5] + h3 * W3[7];
    float d  = dinv[i];
    float d2 = d * d;
    *(float2*)(xw3  + (size_t)i * 2) = make_float2(o0, o1);
    *(float2*)(agg3 + (size_t)i * 2) = make_float2(d2 * o0, d2 * o1);
}

__global__ __launch_bounds__(TPB) void k_out(
    const float* __restrict__ b3, const float* __restrict__ Wc,
    const float* __restrict__ bc,
    const float* __restrict__ agg3,
    float* __restrict__ out, float* __restrict__ y3out, int N) {
    int i = blockIdx.x * TPB + threadIdx.x;
    if (i >= N) return;
    float2 av = *(const float2*)(agg3 + (size_t)i * 2);
    float y0 = fmaxf(av.x + b3[0], 0.f);
    float y1 = fmaxf(av.y + b3[1], 0.f);
    float o[4];
#pragma unroll
    for (int j = 0; j < 4; ++j)
        o[j] = y0 * Wc[0 * 4 + j] + y1 * Wc[1 * 4 + j] + bc[j];
    *(float4*)(out + (size_t)i * 4) = make_float4(o[0], o[1], o[2], o[3]);
    *(float2*)(y3out + (size_t)i * 2) = make_float2(y0, y1);
}

extern "C" void kernel_launch(void* const* d_in, const int* in_sizes, int n_in,
                              void* d_out, int out_size, void* d_ws, size_t ws_size,
                              hipStream_t stream) {
    const float* x  = (const float*)d_in[0];
    const int*   ei = (const int*)d_in[1];   // int32 (harness converts integer inputs)
    const float* W1 = (const float*)d_in[2];
    const float* b1 = (const float*)d_in[3];
    const float* W2 = (const float*)d_in[4];
    const float* b2 = (const float*)d_in[5];
    const float* W3 = (const float*)d_in[6];
    const float* b3 = (const float*)d_in[7];
    const float* Wc = (const float*)d_in[8];
    const float* bc = (const float*)d_in[9];

    const int N = in_sizes[0] / 128;
    const int E = in_sizes[1] / 2;

    const int* row = ei;
    const int* col = ei + (size_t)E;

    const int NB  = (N + SPAN - 1) / SPAN;        // dest buckets (391)
    const int M   = NB * PART_B;                  // flattened hist size (~50K)
    const int PBE = (E + PART_B - 1) / PART_B;    // edges per partition block

    float* out   = (float*)d_out;                  // [N,4]
    float* y3out = (float*)d_out + (size_t)N * 4;  // [N,2]

    const int nblkN = (N + TPB - 1) / TPB;
    const int nblkE = (E + TPB - 1) / TPB;
    const int nblkW = (N * 64 + TPB - 1) / TPB;    // wave-per-node
    const int nblkG = (N * 16 + TPB - 1) / TPB;    // 16 threads/node
    const int nblkM = (M + 1 + TPB - 1) / TPB;
    const int nblkS = (M + SCAN_B - 1) / SCAN_B;   // scan blocks

    // Bucket-path carve (~56.3MB). Hflat is scanned in place (becomes O).
    size_t off = 0;
    auto carve = [&](size_t bytes) -> void* {
        void* r = (void*)((char*)d_ws + off);
        off += (bytes + 255) & ~(size_t)255;
        return r;
    };
    float*        dinv    = (float*)carve((size_t)N * 4);
    float*        dxw1    = (float*)carve((size_t)N * 4 * 4);
    float*        dxw2    = (float*)carve((size_t)N * 4 * 4);
    float*        dxw3    = (float*)carve((size_t)N * 2 * 4);
    unsigned int* indptr  = (unsigned int*)carve(((size_t)N + 1) * 4);
    uint32_t*     bsum    = (uint32_t*)carve(256 * 4);
    uint32_t*     Hflat   = (uint32_t*)carve(((size_t)M + 1) * 4);  // -> O in place
    uint32_t*     bpack   = (uint32_t*)carve((size_t)E * 4);
    int*          csr_row = (int*)carve((size_t)E * 4);
    bool use_bucket = (off <= ws_size) && (NB <= 1024) && (N < (1 << 24));

    if (use_bucket) {
        p_hist<<<PART_B, PART_T, 0, stream>>>(col, Hflat, NB, E, PBE);
        k_scan1<<<nblkS, SCAN_T, 0, stream>>>(Hflat, Hflat, bsum, M);       // in-place
        k_scan2<<<1, 32, 0, stream>>>(bsum, nblkS);
        k_scan3<<<nblkM, TPB, 0, stream>>>(Hflat, bsum, Hflat, M, E);       // in-place
        p_part<<<PART_B, PART_T, 0, stream>>>(row, col, Hflat, bpack, NB, E, PBE);
        p_sort<<<NB, PART_T, 0, stream>>>(bpack, Hflat, csr_row, indptr, dinv, NB, N, E);
        k_xw1d<<<nblkW, TPB, 0, stream>>>(x, W1, dinv, dxw1, N);
        k_gather44<<<nblkG, TPB, 0, stream>>>(indptr, csr_row, dinv, dxw1, b1, W2, dxw2, N);
        k_gather42<<<nblkG, TPB, 0, stream>>>(indptr, csr_row, dinv, dxw2, b2, W3, dxw3, N);
        k_gather2out<<<nblkG, TPB, 0, stream>>>(indptr, csr_row, dinv, dxw3, b3, Wc, bc,
                                                out, y3out, N);
    } else {
        // R3 verified atomic-push fallback: recarve from base (~6MB).
        size_t foff = 0;
        auto fcarve = [&](size_t bytes) -> void* {
            void* r = (void*)((char*)d_ws + foff);
            foff += (bytes + 255) & ~(size_t)255;
            return r;
        };
        unsigned int* deg   = (unsigned int*)fcarve((size_t)N * 4);
        float*        fdinv = (float*)fcarve((size_t)N * 4);
        float*        xw    = (float*)fcarve((size_t)N * 4 * 4);
        float*        agg   = (float*)fcarve((size_t)N * 4 * 4);
        float*        xw3   = (float*)fcarve((size_t)N * 2 * 4);
        float*        agg3  = (float*)fcarve((size_t)N * 2 * 4);
        k_zero_deg<<<nblkN, TPB, 0, stream>>>(deg, N);
        k_deg<<<nblkE, TPB, 0, stream>>>(col, deg, E);
        k_dinv<<<nblkN, TPB, 0, stream>>>(deg, fdinv, N);
        k_xw1<<<nblkW, TPB, 0, stream>>>(x, W1, fdinv, xw, agg, N);
        k_prop4<<<nblkE, TPB, 0, stream>>>(row, col, fdinv, xw, agg, E);
        k_node2<<<nblkN, TPB, 0, stream>>>(b1, W2, fdinv, xw, agg, N);
        k_prop4<<<nblkE, TPB, 0, stream>>>(row, col, fdinv, xw, agg, E);
        k_node3<<<nblkN, TPB, 0, stream>>>(b2, W3, fdinv, agg, xw3, agg3, N);
        k_prop2<<<nblkE, TPB, 0, stream>>>(row, col, fdinv, xw3, agg3, E);
        k_out<<<nblkN, TPB, 0, stream>>>(b3, Wc, bc, agg3, out, y3out, N);
    }
}

// Round 9
// 208.039 us; speedup vs baseline: 1.2605x; 1.2605x over previous
//
#include <hip/hip_runtime.h>
#include <stdint.h>

#define TPB 256
#define SPAN 256        // nodes per dest bucket (bucket = col>>8)
#define LSH 8           // log2(SPAN)
#define PART_B 256      // partition blocks (256 -> one per CU)
#define PART_T 1024     // threads in hist/partition/sort kernels
#define SCAN_T 1024
#define SCAN_B 4096     // elements per scan block (1024 thr x 4)
#define SORT_CAP 18432  // words of dynamic LDS sort buffer (72KB); window ~16384±128

// ---------------------------------------------------------------------------
// GCN 3-layer forward on MI355X.
// R9: two fixes from R8 counters.
// (1) p_part was occupancy-bound (128 blocks = half the CUs, 19% occ,
//     0.64TB/s despite amp fixed): PART_B 128->256 at SPAN=256 -> all CUs,
//     256B runs (amp ~1.5x predicted).
// (2) p_sort's 6.4M random 4B global stores -> counting-sort into 72KB
//     dynamic-LDS buffer, then coalesced contiguous write-out (64x fewer
//     store transactions, no partial-line evictions). Per-bucket fallback
//     to direct stores if window > SORT_CAP (deterministic).
// Pipeline: p_hist | scan(in place) | p_part | p_sort | xw1d | 3x CSR gather.
// agg[c] = dinv[c]*(sum_in dxw[r] + dxw[c]), dxw = dinv*(h@W).
// WS ~56.3MB. R3 atomic-push fallback kept.
// ---------------------------------------------------------------------------

// ---------------- bucket partition ----------------

__global__ __launch_bounds__(PART_T) void p_hist(
    const int* __restrict__ col, uint32_t* __restrict__ H,
    int NB, int E, int PBE) {
    __shared__ uint32_t cnt[1024];
    for (int i = threadIdx.x; i < NB; i += PART_T) cnt[i] = 0u;
    __syncthreads();
    int blk = blockIdx.x;
    int s = blk * PBE, e = min(E, s + PBE);
    for (int i = s + threadIdx.x; i < e; i += PART_T)
        atomicAdd(&cnt[col[i] >> LSH], 1u);
    __syncthreads();
    for (int i = threadIdx.x; i < NB; i += PART_T)
        H[(size_t)i * PART_B + blk] = cnt[i];
}

__global__ __launch_bounds__(SCAN_T) void k_scan1(
    const unsigned int* __restrict__ in, unsigned int* __restrict__ partial,
    unsigned int* __restrict__ bsum, int M) {
    __shared__ unsigned int sm[SCAN_T];
    int tid  = threadIdx.x;
    int base = blockIdx.x * SCAN_B + tid * 4;
    unsigned int v0 = (base + 0 < M) ? in[base + 0] : 0u;
    unsigned int v1 = (base + 1 < M) ? in[base + 1] : 0u;
    unsigned int v2 = (base + 2 < M) ? in[base + 2] : 0u;
    unsigned int v3 = (base + 3 < M) ? in[base + 3] : 0u;
    unsigned int s = v0 + v1 + v2 + v3;
    sm[tid] = s;
    __syncthreads();
    for (int off = 1; off < SCAN_T; off <<= 1) {
        unsigned int t = (tid >= off) ? sm[tid - off] : 0u;
        __syncthreads();
        sm[tid] += t;
        __syncthreads();
    }
    unsigned int excl = sm[tid] - s;
    if (base + 0 < M) partial[base + 0] = excl;
    if (base + 1 < M) partial[base + 1] = excl + v0;
    if (base + 2 < M) partial[base + 2] = excl + v0 + v1;
    if (base + 3 < M) partial[base + 3] = excl + v0 + v1 + v2;
    if (tid == SCAN_T - 1) bsum[blockIdx.x] = sm[SCAN_T - 1];
}

__global__ void k_scan2(unsigned int* __restrict__ bsum, int nb) {
    if (threadIdx.x == 0 && blockIdx.x == 0) {
        unsigned int run = 0;
        for (int i = 0; i < nb; ++i) {
            unsigned int t = bsum[i];
            bsum[i] = run;
            run += t;
        }
    }
}

__global__ __launch_bounds__(TPB) void k_scan3(
    const unsigned int* __restrict__ partial, const unsigned int* __restrict__ bsum,
    unsigned int* __restrict__ outp, int M, int E) {
    int i = blockIdx.x * TPB + threadIdx.x;
    if (i < M) outp[i] = partial[i] + bsum[i / SCAN_B];
    if (i == 0) outp[M] = (unsigned int)E;
}

// Partition: write bpack[slot] = (row<<LSH)|ldest, bucket-grouped.
__global__ __launch_bounds__(PART_T) void p_part(
    const int* __restrict__ row, const int* __restrict__ col,
    const uint32_t* __restrict__ O, uint32_t* __restrict__ bpack,
    int NB, int E, int PBE) {
    __shared__ uint32_t cur[1024];
    int blk = blockIdx.x;
    for (int i = threadIdx.x; i < NB; i += PART_T)
        cur[i] = O[(size_t)i * PART_B + blk];
    __syncthreads();
    int s = blk * PBE, e = min(E, s + PBE);
    for (int i = s + threadIdx.x; i < e; i += PART_T) {
        int c = col[i];
        uint32_t slot = atomicAdd(&cur[c >> LSH], 1u);
        bpack[slot] = ((uint32_t)row[i] << LSH) | (uint32_t)(c & (SPAN - 1));
    }
}

// Per-bucket counting sort via LDS staging + coalesced write-out.
// Emits indptr + dinv. Fallback to direct stores if window > SORT_CAP.
extern __shared__ uint32_t sort_buf[];
__global__ __launch_bounds__(PART_T) void p_sort(
    const uint32_t* __restrict__ bpack, const uint32_t* __restrict__ O,
    int* __restrict__ csr_row, unsigned int* __restrict__ indptr,
    float* __restrict__ dinv, int NB, int N, int E) {
    __shared__ uint32_t hist[SPAN];
    __shared__ uint32_t cur[SPAN];
    int b = blockIdx.x;
    int t = threadIdx.x;
    if (t < SPAN) hist[t] = 0u;
    __syncthreads();
    uint32_t s = O[(size_t)b * PART_B];
    uint32_t e = (b + 1 < NB) ? O[(size_t)(b + 1) * PART_B] : (uint32_t)E;
    uint32_t W = e - s;
    for (uint32_t i = s + t; i < e; i += PART_T)
        atomicAdd(&hist[bpack[i] & (SPAN - 1)], 1u);
    __syncthreads();
    if (t < SPAN) cur[t] = hist[t];
    __syncthreads();
    for (int off = 1; off < SPAN; off <<= 1) {  // Hillis-Steele inclusive scan
        uint32_t v = (t < SPAN && t >= off) ? cur[t - off] : 0u;
        __syncthreads();
        if (t < SPAN) cur[t] += v;
        __syncthreads();
    }
    if (t < SPAN) {
        uint32_t excl = cur[t] - hist[t];
        int n = b * SPAN + t;
        if (n < N) {
            indptr[n] = s + excl;
            dinv[n]   = rsqrtf((float)(hist[t] + 1u));  // +1 = self loop
            if (n == N - 1) indptr[N] = (unsigned int)E;
        }
        cur[t] = excl;  // LOCAL cursor (window-relative)
    }
    __syncthreads();
    if (W <= SORT_CAP) {
        // scatter into LDS, then stream out coalesced
        for (uint32_t i = s + t; i < e; i += PART_T) {
            uint32_t v = bpack[i];
            uint32_t slot = atomicAdd(&cur[v & (SPAN - 1)], 1u);
            sort_buf[slot] = v >> LSH;
        }
        __syncthreads();
        for (uint32_t j = t; j < W; j += PART_T)
            csr_row[s + j] = (int)sort_buf[j];
    } else {
        // rare fallback: direct (scattered) stores
        for (uint32_t i = s + t; i < e; i += PART_T) {
            uint32_t v = bpack[i];
            uint32_t slot = atomicAdd(&cur[v & (SPAN - 1)], 1u);
            csr_row[s + slot] = (int)(v >> LSH);
        }
    }
}

// ---------------- node / gather kernels (main path) ----------------

// dxw1 = dinv * (x @ W1), wave per node.
__global__ __launch_bounds__(TPB) void k_xw1d(
    const float* __restrict__ x, const float* __restrict__ W1,
    const float* __restrict__ dinv, float* __restrict__ dxw1, int N) {
    __shared__ float sW[512];  // 128 x 4
    for (int t = threadIdx.x; t < 512; t += TPB) sW[t] = W1[t];
    __syncthreads();
    int gid  = blockIdx.x * TPB + threadIdx.x;
    int node = gid >> 6;
    int lane = threadIdx.x & 63;
    if (node >= N) return;
    float2 v = *(const float2*)(x + (size_t)node * 128 + 2 * lane);
    const float* w0 = &sW[(2 * lane) * 4];
    const float* w1 = &sW[(2 * lane + 1) * 4];
    float a[4];
#pragma unroll
    for (int j = 0; j < 4; ++j) a[j] = v.x * w0[j] + v.y * w1[j];
#pragma unroll
    for (int off = 32; off > 0; off >>= 1) {
#pragma unroll
        for (int j = 0; j < 4; ++j) a[j] += __shfl_down(a[j], off);
    }
    if (lane == 0) {
        float d = dinv[node];
        *(float4*)(dxw1 + (size_t)node * 4) =
            make_float4(d * a[0], d * a[1], d * a[2], d * a[3]);
    }
}

// Gather layer (4-wide in / 4-wide out): 16 threads/node.
__global__ __launch_bounds__(TPB) void k_gather44(
    const unsigned int* __restrict__ indptr, const int* __restrict__ csr_row,
    const float* __restrict__ dinv, const float* __restrict__ dxw_in,
    const float* __restrict__ b, const float* __restrict__ W,
    float* __restrict__ dxw_out, int N) {
    int gid  = blockIdx.x * TPB + threadIdx.x;
    int node = gid >> 4;
    int sub  = gid & 15;
    if (node >= N) return;
    int e0 = (int)indptr[node], e1 = (int)indptr[node + 1];
    float4 acc = make_float4(0.f, 0.f, 0.f, 0.f);
    for (int j = e0 + sub; j < e1; j += 16) {
        int r = csr_row[j];
        float4 m = *(const float4*)(dxw_in + (size_t)r * 4);
        acc.x += m.x; acc.y += m.y; acc.z += m.z; acc.w += m.w;
    }
#pragma unroll
    for (int off = 1; off < 16; off <<= 1) {
        acc.x += __shfl_xor(acc.x, off);
        acc.y += __shfl_xor(acc.y, off);
        acc.z += __shfl_xor(acc.z, off);
        acc.w += __shfl_xor(acc.w, off);
    }
    if (sub == 0) {
        float d = dinv[node];
        float4 sv = *(const float4*)(dxw_in + (size_t)node * 4);
        float h0 = fmaxf(d * (acc.x + sv.x) + b[0], 0.f);
        float h1 = fmaxf(d * (acc.y + sv.y) + b[1], 0.f);
        float h2 = fmaxf(d * (acc.z + sv.z) + b[2], 0.f);
        float h3 = fmaxf(d * (acc.w + sv.w) + b[3], 0.f);
        float o[4];
#pragma unroll
        for (int j = 0; j < 4; ++j)
            o[j] = h0 * W[0 * 4 + j] + h1 * W[1 * 4 + j] +
                   h2 * W[2 * 4 + j] + h3 * W[3 * 4 + j];
        *(float4*)(dxw_out + (size_t)node * 4) =
            make_float4(d * o[0], d * o[1], d * o[2], d * o[3]);
    }
}

// Gather layer (4-wide in / 2-wide out): 16 threads/node.
__global__ __launch_bounds__(TPB) void k_gather42(
    const unsigned int* __restrict__ indptr, const int* __restrict__ csr_row,
    const float* __restrict__ dinv, const float* __restrict__ dxw_in,
    const float* __restrict__ b, const float* __restrict__ W,
    float* __restrict__ dxw_out, int N) {
    int gid  = blockIdx.x * TPB + threadIdx.x;
    int node = gid >> 4;
    int sub  = gid & 15;
    if (node >= N) return;
    int e0 = (int)indptr[node], e1 = (int)indptr[node + 1];
    float4 acc = make_float4(0.f, 0.f, 0.f, 0.f);
    for (int j = e0 + sub; j < e1; j += 16) {
        int r = csr_row[j];
        float4 m = *(const float4*)(dxw_in + (size_t)r * 4);
        acc.x += m.x; acc.y += m.y; acc.z += m.z; acc.w += m.w;
    }
#pragma unroll
    for (int off = 1; off < 16; off <<= 1) {
        acc.x += __shfl_xor(acc.x, off);
        acc.y += __shfl_xor(acc.y, off);
        acc.z += __shfl_xor(acc.z, off);
        acc.w += __shfl_xor(acc.w, off);
    }
    if (sub == 0) {
        float d = dinv[node];
        float4 sv = *(const float4*)(dxw_in + (size_t)node * 4);
        float h0 = fmaxf(d * (acc.x + sv.x) + b[0], 0.f);
        float h1 = fmaxf(d * (acc.y + sv.y) + b[1], 0.f);
        float h2 = fmaxf(d * (acc.z + sv.z) + b[2], 0.f);
        float h3 = fmaxf(d * (acc.w + sv.w) + b[3], 0.f);
        float o0 = h0 * W[0] + h1 * W[2] + h2 * W[4] + h3 * W[6];
        float o1 = h0 * W[1] + h1 * W[3] + h2 * W[5] + h3 * W[7];
        *(float2*)(dxw_out + (size_t)node * 2) = make_float2(d * o0, d * o1);
    }
}

// Final gather (2-wide): 16 threads/node; writes both outputs.
__global__ __launch_bounds__(TPB) void k_gather2out(
    const unsigned int* __restrict__ indptr, const int* __restrict__ csr_row,
    const float* __restrict__ dinv, const float* __restrict__ dxw3,
    const float* __restrict__ b3, const float* __restrict__ Wc,
    const float* __restrict__ bc,
    float* __restrict__ out, float* __restrict__ y3out, int N) {
    int gid  = blockIdx.x * TPB + threadIdx.x;
    int node = gid >> 4;
    int sub  = gid & 15;
    if (node >= N) return;
    int e0 = (int)indptr[node], e1 = (int)indptr[node + 1];
    float ax = 0.f, ay = 0.f;
    for (int j = e0 + sub; j < e1; j += 16) {
        int r = csr_row[j];
        float2 m = *(const float2*)(dxw3 + (size_t)r * 2);
        ax += m.x; ay += m.y;
    }
#pragma unroll
    for (int off = 1; off < 16; off <<= 1) {
        ax += __shfl_xor(ax, off);
        ay += __shfl_xor(ay, off);
    }
    if (sub == 0) {
        float d = dinv[node];
        float2 sv = *(const float2*)(dxw3 + (size_t)node * 2);
        float y0 = fmaxf(d * (ax + sv.x) + b3[0], 0.f);
        float y1 = fmaxf(d * (ay + sv.y) + b3[1], 0.f);
        float o[4];
#pragma unroll
        for (int j = 0; j < 4; ++j)
            o[j] = y0 * Wc[0 * 4 + j] + y1 * Wc[1 * 4 + j] + bc[j];
        *(float4*)(out + (size_t)node * 4) = make_float4(o[0], o[1], o[2], o[3]);
        *(float2*)(y3out + (size_t)node * 2) = make_float2(y0, y1);
    }
}

// ---------------- R3 fallback kernels (atomic push path) ----------------

__global__ __launch_bounds__(TPB) void k_zero_deg(unsigned int* __restrict__ deg, int N) {
    int i = blockIdx.x * TPB + threadIdx.x;
    if (i < N) deg[i] = 0u;
}

__global__ __launch_bounds__(TPB) void k_deg(
    const int* __restrict__ col, unsigned int* __restrict__ deg, int E) {
    int e = blockIdx.x * TPB + threadIdx.x;
    if (e >= E) return;
    atomicAdd(&deg[col[e]], 1u);
}

__global__ __launch_bounds__(TPB) void k_dinv(const unsigned int* __restrict__ deg,
                                              float* __restrict__ dinv, int N) {
    int i = blockIdx.x * TPB + threadIdx.x;
    if (i < N) dinv[i] = rsqrtf((float)(deg[i] + 1u));
}

__global__ __launch_bounds__(TPB) void k_xw1(
    const float* __restrict__ x, const float* __restrict__ W1,
    const float* __restrict__ dinv,
    float* __restrict__ xw, float* __restrict__ agg, int N) {
    __shared__ float sW[512];
    for (int t = threadIdx.x; t < 512; t += TPB) sW[t] = W1[t];
    __syncthreads();
    int gid  = blockIdx.x * TPB + threadIdx.x;
    int node = gid >> 6;
    int lane = threadIdx.x & 63;
    if (node >= N) return;
    float2 v = *(const float2*)(x + (size_t)node * 128 + 2 * lane);
    const float* w0 = &sW[(2 * lane) * 4];
    const float* w1 = &sW[(2 * lane + 1) * 4];
    float a[4];
#pragma unroll
    for (int j = 0; j < 4; ++j) a[j] = v.x * w0[j] + v.y * w1[j];
#pragma unroll
    for (int off = 32; off > 0; off >>= 1) {
#pragma unroll
        for (int j = 0; j < 4; ++j) a[j] += __shfl_down(a[j], off);
    }
    if (lane == 0) {
        float d  = dinv[node];
        float d2 = d * d;
        *(float4*)(xw  + (size_t)node * 4) = make_float4(a[0], a[1], a[2], a[3]);
        *(float4*)(agg + (size_t)node * 4) =
            make_float4(d2 * a[0], d2 * a[1], d2 * a[2], d2 * a[3]);
    }
}

__global__ __launch_bounds__(TPB) void k_prop4(
    const int* __restrict__ row, const int* __restrict__ col,
    const float* __restrict__ dinv,
    const float* __restrict__ xw, float* __restrict__ agg, int E) {
    int e = blockIdx.x * TPB + threadIdx.x;
    if (e >= E) return;
    int r = row[e];
    int c = col[e];
    float nv = dinv[r] * dinv[c];
    float4 m = *(const float4*)(xw + (size_t)r * 4);
    float* a = agg + (size_t)c * 4;
    atomicAdd(a + 0, nv * m.x);
    atomicAdd(a + 1, nv * m.y);
    atomicAdd(a + 2, nv * m.z);
    atomicAdd(a + 3, nv * m.w);
}

__global__ __launch_bounds__(TPB) void k_prop2(
    const int* __restrict__ row, const int* __restrict__ col,
    const float* __restrict__ dinv,
    const float* __restrict__ xw2, float* __restrict__ agg2, int E) {
    int e = blockIdx.x * TPB + threadIdx.x;
    if (e >= E) return;
    int r = row[e];
    int c = col[e];
    float nv = dinv[r] * dinv[c];
    float2 m = *(const float2*)(xw2 + (size_t)r * 2);
    float* a = agg2 + (size_t)c * 2;
    atomicAdd(a + 0, nv * m.x);
    atomicAdd(a + 1, nv * m.y);
}

__global__ __launch_bounds__(TPB) void k_node2(
    const float* __restrict__ b1, const float* __restrict__ W2,
    const float* __restrict__ dinv,
    float* __restrict__ xw, float* __restrict__ agg, int N) {
    int i = blockIdx.x * TPB + threadIdx.x;
    if (i >= N) return;
    float4 av = *(const float4*)(agg + (size_t)i * 4);
    float h0 = fmaxf(av.x + b1[0], 0.f);
    float h1 = fmaxf(av.y + b1[1], 0.f);
    float h2 = fmaxf(av.z + b1[2], 0.f);
    float h3 = fmaxf(av.w + b1[3], 0.f);
    float o[4];
#pragma unroll
    for (int j = 0; j < 4; ++j)
        o[j] = h0 * W2[0 * 4 + j] + h1 * W2[1 * 4 + j] +
               h2 * W2[2 * 4 + j] + h3 * W2[3 * 4 + j];
    float d  = dinv[i];
    float d2 = d * d;
    *(float4*)(xw  + (size_t)i * 4) = make_float4(o[0], o[1], o[2], o[3]);
    *(float4*)(agg + (size_t)i * 4) = make_float4(d2 * o[0], d2 * o[1], d2 * o[2], d2 * o[3]);
}

__global__ __launch_bounds__(TPB) void k_node3(
    const float* __restrict__ b2, const float* __restrict__ W3,
    const float* __restrict__ dinv,
    const float* __restrict__ agg,
    float* __restrict__ xw3, float* __restrict__ agg3, int N) {
    int i = blockIdx.x * TPB + threadIdx.x;
    if (i >= N) return;
    float4 av = *(const float4*)(agg + (size_t)i * 4);
    float h0 = fmaxf(av.x + b2[0], 0.f);
    float h1 = fmaxf(av.y + b2[1], 0.f);
    float h2 = fmaxf(av.z + b2[2], 0.f);
    float h3 = fmaxf(av.w + b2[3], 0.f);
    float o0 = h0 * W3[0] + h1 * W3[2] + h2 * W3[4] + h3 * W3[6];
    float o1 = h0 * W3[1] + h1 * W3[3] + h2 * W3[5] + h3 * W3[7];
    float d  = dinv[i];
    float d2 = d * d;
    *(float2*)(xw3  + (size_t)i * 2) = make_float2(o0, o1);
    *(float2*)(agg3 + (size_t)i * 2) = make_float2(d2 * o0, d2 * o1);
}

__global__ __launch_bounds__(TPB) void k_out(
    const float* __restrict__ b3, const float* __restrict__ Wc,
    const float* __restrict__ bc,
    const float* __restrict__ agg3,
    float* __restrict__ out, float* __restrict__ y3out, int N) {
    int i = blockIdx.x * TPB + threadIdx.x;
    if (i >= N) return;
    float2 av = *(const float2*)(agg3 + (size_t)i * 2);
    float y0 = fmaxf(av.x + b3[0], 0.f);
    float y1 = fmaxf(av.y + b3[1], 0.f);
    float o[4];
#pragma unroll
    for (int j = 0; j < 4; ++j)
        o[j] = y0 * Wc[0 * 4 + j] + y1 * Wc[1 * 4 + j] + bc[j];
    *(float4*)(out + (size_t)i * 4) = make_float4(o[0], o[1], o[2], o[3]);
    *(float2*)(y3out + (size_t)i * 2) = make_float2(y0, y1);
}

extern "C" void kernel_launch(void* const* d_in, const int* in_sizes, int n_in,
                              void* d_out, int out_size, void* d_ws, size_t ws_size,
                              hipStream_t stream) {
    const float* x  = (const float*)d_in[0];
    const int*   ei = (const int*)d_in[1];   // int32 (harness converts integer inputs)
    const float* W1 = (const float*)d_in[2];
    const float* b1 = (const float*)d_in[3];
    const float* W2 = (const float*)d_in[4];
    const float* b2 = (const float*)d_in[5];
    const float* W3 = (const float*)d_in[6];
    const float* b3 = (const float*)d_in[7];
    const float* Wc = (const float*)d_in[8];
    const float* bc = (const float*)d_in[9];

    const int N = in_sizes[0] / 128;
    const int E = in_sizes[1] / 2;

    const int* row = ei;
    const int* col = ei + (size_t)E;

    const int NB  = (N + SPAN - 1) / SPAN;        // dest buckets (391)
    const int M   = NB * PART_B;                  // flattened hist size (~100K)
    const int PBE = (E + PART_B - 1) / PART_B;    // edges per partition block

    float* out   = (float*)d_out;                  // [N,4]
    float* y3out = (float*)d_out + (size_t)N * 4;  // [N,2]

    const int nblkN = (N + TPB - 1) / TPB;
    const int nblkE = (E + TPB - 1) / TPB;
    const int nblkW = (N * 64 + TPB - 1) / TPB;    // wave-per-node
    const int nblkG = (N * 16 + TPB - 1) / TPB;    // 16 threads/node
    const int nblkM = (M + 1 + TPB - 1) / TPB;
    const int nblkS = (M + SCAN_B - 1) / SCAN_B;   // scan blocks

    // Bucket-path carve (~56.5MB). Hflat is scanned in place (becomes O).
    size_t off = 0;
    auto carve = [&](size_t bytes) -> void* {
        void* r = (void*)((char*)d_ws + off);
        off += (bytes + 255) & ~(size_t)255;
        return r;
    };
    float*        dinv    = (float*)carve((size_t)N * 4);
    float*        dxw1    = (float*)carve((size_t)N * 4 * 4);
    float*        dxw2    = (float*)carve((size_t)N * 4 * 4);
    float*        dxw3    = (float*)carve((size_t)N * 2 * 4);
    unsigned int* indptr  = (unsigned int*)carve(((size_t)N + 1) * 4);
    uint32_t*     bsum    = (uint32_t*)carve(256 * 4);
    uint32_t*     Hflat   = (uint32_t*)carve(((size_t)M + 1) * 4);  // -> O in place
    uint32_t*     bpack   = (uint32_t*)carve((size_t)E * 4);
    int*          csr_row = (int*)carve((size_t)E * 4);
    bool use_bucket = (off <= ws_size) && (NB <= 1024) && (N < (1 << 23));

    if (use_bucket) {
        size_t sort_lds = (size_t)SORT_CAP * 4;  // 72KB dynamic
        hipFuncSetAttribute((const void*)p_sort,
                            hipFuncAttributeMaxDynamicSharedMemorySize,
                            (int)sort_lds);
        p_hist<<<PART_B, PART_T, 0, stream>>>(col, Hflat, NB, E, PBE);
        k_scan1<<<nblkS, SCAN_T, 0, stream>>>(Hflat, Hflat, bsum, M);       // in-place
        k_scan2<<<1, 32, 0, stream>>>(bsum, nblkS);
        k_scan3<<<nblkM, TPB, 0, stream>>>(Hflat, bsum, Hflat, M, E);       // in-place
        p_part<<<PART_B, PART_T, 0, stream>>>(row, col, Hflat, bpack, NB, E, PBE);
        p_sort<<<NB, PART_T, sort_lds, stream>>>(bpack, Hflat, csr_row, indptr,
                                                 dinv, NB, N, E);
        k_xw1d<<<nblkW, TPB, 0, stream>>>(x, W1, dinv, dxw1, N);
        k_gather44<<<nblkG, TPB, 0, stream>>>(indptr, csr_row, dinv, dxw1, b1, W2, dxw2, N);
        k_gather42<<<nblkG, TPB, 0, stream>>>(indptr, csr_row, dinv, dxw2, b2, W3, dxw3, N);
        k_gather2out<<<nblkG, TPB, 0, stream>>>(indptr, csr_row, dinv, dxw3, b3, Wc, bc,
                                                out, y3out, N);
    } else {
        // R3 verified atomic-push fallback: recarve from base (~6MB).
        size_t foff = 0;
        auto fcarve = [&](size_t bytes) -> void* {
            void* r = (void*)((char*)d_ws + foff);
            foff += (bytes + 255) & ~(size_t)255;
            return r;
        };
        unsigned int* deg   = (unsigned int*)fcarve((size_t)N * 4);
        float*        fdinv = (float*)fcarve((size_t)N * 4);
        float*        xw    = (float*)fcarve((size_t)N * 4 * 4);
        float*        agg   = (float*)fcarve((size_t)N * 4 * 4);
        float*        xw3   = (float*)fcarve((size_t)N * 2 * 4);
        float*        agg3  = (float*)fcarve((size_t)N * 2 * 4);
        k_zero_deg<<<nblkN, TPB, 0, stream>>>(deg, N);
        k_deg<<<nblkE, TPB, 0, stream>>>(col, deg, E);
        k_dinv<<<nblkN, TPB, 0, stream>>>(deg, fdinv, N);
        k_xw1<<<nblkW, TPB, 0, stream>>>(x, W1, fdinv, xw, agg, N);
        k_prop4<<<nblkE, TPB, 0, stream>>>(row, col, fdinv, xw, agg, E);
        k_node2<<<nblkN, TPB, 0, stream>>>(b1, W2, fdinv, xw, agg, N);
        k_prop4<<<nblkE, TPB, 0, stream>>>(row, col, fdinv, xw, agg, E);
        k_node3<<<nblkN, TPB, 0, stream>>>(b2, W3, fdinv, agg, xw3, agg3, N);
        k_prop2<<<nblkE, TPB, 0, stream>>>(row, col, fdinv, xw3, agg3, E);
        k_out<<<nblkN, TPB, 0, stream>>>(b3, Wc, bc, agg3, out, y3out, N);
    }
}